// Round 8
// baseline (28557.178 us; speedup 1.0000x reference)
//
#include <hip/hip_runtime.h>
#include <math.h>

// Round 8: conv3x3 v4 = R6's grid density + R7's 8oc amortization.
// 128-thread blocks, 64px x 64oc tile, thread = 4px x 8oc, inputs fp32 LDS,
// weights fp64 LDS, __launch_bounds__(128,4). FMA order per output unchanged
// (ic0 asc, icr asc, ky asc, kx asc) -> z bit-exact vs passing rounds.
// Anchors: fp64 acc + fp32 op-order epilogue; VQ numpy-fp32 emulation.

static constexpr float kBNF = 0.9999950000374997f;

// ---------------------------------------------------------------- conv0: 1->128, 3x3, s1, relu (B=1)
__global__ __launch_bounds__(320) void conv0_k(const float* __restrict__ x,
                                               const float* __restrict__ w,
                                               const float* __restrict__ b,
                                               float* __restrict__ out) {
  const int H = 320, W = 320, OC = 128;
  int oy = blockIdx.x;
  int tx = threadIdx.x;
  __shared__ float in_s[3][W + 2];
  __shared__ float w_s[128 * 9];
  __shared__ float b_s[128];
  for (int e = tx; e < 3 * (W + 2); e += 320) {
    int r = e / (W + 2), c = e % (W + 2);
    int iy = oy + r - 1, ix = c - 1;
    float v = 0.f;
    if (iy >= 0 && iy < H && ix >= 0 && ix < W) v = x[iy * W + ix];
    in_s[r][c] = v;
  }
  for (int e = tx; e < 128 * 9; e += 320) w_s[e] = w[e];
  for (int e = tx; e < 128; e += 320) b_s[e] = b[e];
  __syncthreads();
  double iv[9];
#pragma unroll
  for (int r = 0; r < 3; ++r)
#pragma unroll
    for (int c = 0; c < 3; ++c) iv[r * 3 + c] = (double)in_s[r][tx + c];
  for (int oc = 0; oc < OC; ++oc) {
    double acc = 0.0;
#pragma unroll
    for (int t = 0; t < 9; ++t) acc = fma((double)w_s[oc * 9 + t], iv[t], acc);
    float v32 = (float)(acc + (double)b_s[oc]);
    v32 = __fmul_rn(v32, kBNF);
    out[(oc * H + oy) * W + tx] = fmaxf(v32, 0.f);
  }
}

// ---------------------------------------------------------------- 3x3 conv v4
template <int S, bool RELU, bool HAS_SKIP>
__global__ __launch_bounds__(128, 4) void conv3x3_k(
    const float* __restrict__ in, const float* __restrict__ w,
    const float* __restrict__ bias, const float* __restrict__ skip,
    float* __restrict__ out, int IC, int IH, int IW, int OC, int OH, int OW) {
  // S=1: in_f[icr][ky][68] plain cols (66 used)
  // S=2: in_f[icr][ky][136]: [0..67]=even cols, [68..135]=odd cols
  __shared__ float in_f[4][3][(S == 1) ? 68 : 136];
  __shared__ double w_d[4][9][64];
  int t = threadIdx.x;
  int ox0 = blockIdx.x * 64;
  int oy = blockIdx.y;
  int oc0 = blockIdx.z * 64;
  int oc8 = (t >> 4) * 8, px4 = (t & 15) * 4;
  double acc[8][4] = {};
  const int NCOL = 64 * S + 2;  // 66 or 130
  const int NIN = 4 * 3 * NCOL;
  for (int ic0 = 0; ic0 < IC; ic0 += 4) {
    __syncthreads();
    for (int e = t; e < NIN; e += 128) {
      int icr = e / (3 * NCOL);
      int rem = e - icr * (3 * NCOL);
      int r = rem / NCOL, c = rem - r * NCOL;
      int iy = oy * S - 1 + r;
      int ix = ox0 * S - 1 + c;
      float v = 0.f;
      if (iy >= 0 && iy < IH && ix >= 0 && ix < IW)
        v = in[((ic0 + icr) * IH + iy) * IW + ix];
      if (S == 1)
        in_f[icr][r][c] = v;
      else
        in_f[icr][r][(c & 1) * 68 + (c >> 1)] = v;
    }
    for (int e = t; e < 4 * 9 * 64; e += 128) {
      int ocr = e & 63;
      int rem = e >> 6;
      int tap = rem % 9, icr = rem / 9;
      w_d[icr][tap][ocr] = (double)w[((oc0 + ocr) * IC + ic0 + icr) * 9 + tap];
    }
    __syncthreads();
#pragma unroll
    for (int icr = 0; icr < 4; ++icr) {
#pragma unroll
      for (int ky = 0; ky < 3; ++ky) {
        double iv[9];
        if (S == 1) {
          float4 va = *reinterpret_cast<const float4*>(&in_f[icr][ky][px4]);
          float2 vb = *reinterpret_cast<const float2*>(&in_f[icr][ky][px4 + 4]);
          iv[0] = (double)va.x; iv[1] = (double)va.y; iv[2] = (double)va.z;
          iv[3] = (double)va.w; iv[4] = (double)vb.x; iv[5] = (double)vb.y;
        } else {
          float4 ve = *reinterpret_cast<const float4*>(&in_f[icr][ky][px4]);
          float se = in_f[icr][ky][px4 + 4];
          float4 vo = *reinterpret_cast<const float4*>(&in_f[icr][ky][68 + px4]);
          iv[0] = (double)ve.x; iv[1] = (double)ve.y; iv[2] = (double)ve.z;
          iv[3] = (double)ve.w; iv[4] = (double)se;
          iv[5] = (double)vo.x; iv[6] = (double)vo.y; iv[7] = (double)vo.z;
          iv[8] = (double)vo.w;
        }
#pragma unroll
        for (int kx = 0; kx < 3; ++kx) {
          const double* wp = &w_d[icr][ky * 3 + kx][oc8];
          double4 w0 = *reinterpret_cast<const double4*>(wp);
          double4 w1 = *reinterpret_cast<const double4*>(wp + 4);
          const double* wr0 = (const double*)&w0;
          const double* wr1 = (const double*)&w1;
#pragma unroll
          for (int p = 0; p < 4; ++p) {
            double ivv;
            if (S == 1) {
              ivv = iv[p + kx];
            } else {
              ivv = (kx == 0) ? iv[p] : (kx == 1) ? iv[5 + p] : iv[p + 1];
            }
#pragma unroll
            for (int o = 0; o < 4; ++o) {
              acc[o][p] = fma(wr0[o], ivv, acc[o][p]);
              acc[o + 4][p] = fma(wr1[o], ivv, acc[o + 4][p]);
            }
          }
        }
      }
    }
  }
  int opx = ox0 + px4;
  if (opx < OW) {
#pragma unroll
    for (int o = 0; o < 8; ++o) {
      int oc = oc0 + oc8 + o;
      double bv = (double)bias[oc];
      size_t base = ((size_t)oc * OH + oy) * OW + opx;
      float4 rv;
      float* rp = (float*)&rv;
#pragma unroll
      for (int p = 0; p < 4; ++p) {
        float v32 = (float)(acc[o][p] + bv);   // identical fp32 epilogue (bit-exact z)
        v32 = __fmul_rn(v32, kBNF);
        if (HAS_SKIP) v32 = __fadd_rn(v32, skip[base + p]);
        if (RELU) v32 = fmaxf(v32, 0.f);
        rp[p] = v32;
      }
      *reinterpret_cast<float4*>(&out[base]) = rv;
    }
  }
}

// ---------------------------------------------------------------- 1x1 conv, fp64 acc, fp32 epilogue
template <int S, bool RELU>
__global__ __launch_bounds__(256) void conv1x1_k(
    const float* __restrict__ in, const float* __restrict__ w,
    const float* __restrict__ bias, float* __restrict__ out,
    int IC, int IH, int IW, int OC, int OH, int OW) {
  __shared__ float in_s[16][64];
  __shared__ float w_s[16][64];
  const int P = OH * OW;
  int t = threadIdx.x;
  int p0 = blockIdx.x * 64;
  int oc0 = blockIdx.y * 64;
  int oc4 = (t >> 4) * 4, px4 = (t & 15) * 4;
  double acc[4][4] = {};
  for (int ic0 = 0; ic0 < IC; ic0 += 16) {
    __syncthreads();
    {
      int e = t;
#pragma unroll
      for (int k = 0; k < 4; ++k, e += 256) {
        int icr = e >> 6, pxr = e & 63;
        int p = p0 + pxr;
        float v = 0.f;
        if (p < P) {
          int oy = p / OW, ox = p % OW;
          v = in[((ic0 + icr) * IH + oy * S) * IW + ox * S];
        }
        in_s[icr][pxr] = v;
      }
      e = t;
#pragma unroll
      for (int k = 0; k < 4; ++k, e += 256) {
        int icr = e >> 6, ocr = e & 63;
        w_s[icr][ocr] = w[(oc0 + ocr) * IC + ic0 + icr];
      }
    }
    __syncthreads();
#pragma unroll
    for (int icr = 0; icr < 16; ++icr) {
      float4 iv = *reinterpret_cast<const float4*>(&in_s[icr][px4]);
      float4 wv = *reinterpret_cast<const float4*>(&w_s[icr][oc4]);
      const float* ip = (const float*)&iv;
      const float* wp = (const float*)&wv;
#pragma unroll
      for (int o = 0; o < 4; ++o)
#pragma unroll
        for (int p = 0; p < 4; ++p)
          acc[o][p] = fma((double)wp[o], (double)ip[p], acc[o][p]);
    }
  }
  int p = p0 + px4;
  if (p < P) {
    int oy = p / OW, ox = p % OW;
#pragma unroll
    for (int o = 0; o < 4; ++o) {
      int oc = oc0 + oc4 + o;
      double bv = (double)bias[oc];
      float4 rv;
      float* rp = (float*)&rv;
#pragma unroll
      for (int pp = 0; pp < 4; ++pp) {
        float v32 = (float)(acc[o][pp] + bv);
        v32 = __fmul_rn(v32, kBNF);
        if (RELU) v32 = fmaxf(v32, 0.f);
        rp[pp] = v32;
      }
      *reinterpret_cast<float4*>(&out[((size_t)oc * OH + oy) * OW + ox]) = rv;
    }
  }
}

// ---------------------------------------------------------------- ConvT weight transpose: w2[kyb][ic][ty][kx][OC]
__global__ __launch_bounds__(256) void prep_w2_k(const float* __restrict__ w,
                                                 float* __restrict__ w2,
                                                 int IC, int OC) {
  int i = blockIdx.x * 256 + threadIdx.x;
  int total = IC * OC * 16;
  if (i >= total) return;
  int oc = i % OC;
  int r = i / OC;
  int kx = r & 3; r >>= 2;
  int ty = r & 1; r >>= 1;
  int ic = r % IC;
  int kyb = r / IC;
  int ky = kyb + 2 * ty;
  w2[i] = w[((size_t)ic * OC + oc) * 16 + ky * 4 + kx];
}

// ---------------------------------------------------------------- ConvTranspose2d k4 s2 p1, relu (decoder, fp32), ICS=8
__global__ __launch_bounds__(256) void convt_k(
    const float* __restrict__ in, const float* __restrict__ w2,
    const float* __restrict__ bias, float* __restrict__ out,
    int IC, int IH, int IW, int OC, int OH, int OW) {
  __shared__ float in_s[8][2][34];
  __shared__ float w_s[8][2][4][64];
  int t = threadIdx.x;
  int ox0 = blockIdx.x * 64;
  int oy = blockIdx.y;
  int oc0 = blockIdx.z * 64;
  int oc4 = (t >> 4) * 4, px4 = (t & 15) * 4;
  int kyb = (oy & 1) ? 0 : 1;
  int c0 = ox0 >> 1;
  const float* w2b = w2 + (size_t)kyb * IC * 8 * OC;  // [ic][ty][kx][OC]
  float acc[4][4] = {};
  for (int ic0 = 0; ic0 < IC; ic0 += 8) {
    __syncthreads();
    for (int e = t; e < 8 * 2 * 34; e += 256) {
      int icr = e / 68;
      int rem = e - icr * 68;
      int ty = rem / 34, cc = rem - ty * 34;
      int ky = kyb + 2 * ty;
      int iy = (oy + 1 - ky) >> 1;
      int ix = c0 - 1 + cc;
      float v = 0.f;
      if (iy >= 0 && iy < IH && ix >= 0 && ix < IW)
        v = in[((ic0 + icr) * IH + iy) * IW + ix];
      in_s[icr][ty][cc] = v;
    }
    {
      int e = t;
#pragma unroll
      for (int k = 0; k < 16; ++k, e += 256) {
        int icr = e >> 9;
        int rem = e & 511;
        int ty = rem >> 8;
        int kx = (rem >> 6) & 3;
        int ocr = rem & 63;
        w_s[icr][ty][kx][ocr] =
            w2b[((((size_t)(ic0 + icr)) * 2 + ty) * 4 + kx) * OC + oc0 + ocr];
      }
    }
    __syncthreads();
#pragma unroll
    for (int icr = 0; icr < 8; ++icr) {
      float4 wv[2][4];
#pragma unroll
      for (int ty = 0; ty < 2; ++ty)
#pragma unroll
        for (int kx = 0; kx < 4; ++kx)
          wv[ty][kx] = *reinterpret_cast<const float4*>(&w_s[icr][ty][kx][oc4]);
#pragma unroll
      for (int p = 0; p < 4; ++p) {
        int hr = (px4 + p) >> 1;
        int kxa = (p & 1) ? 0 : 1;
        int kxb = (p & 1) ? 2 : 3;
        int ca = (p & 1) ? hr + 2 : hr + 1;
        int cb2 = (p & 1) ? hr + 1 : hr;
#pragma unroll
        for (int ty = 0; ty < 2; ++ty) {
          float sa = in_s[icr][ty][ca];
          float sb = in_s[icr][ty][cb2];
          const float* wa = (const float*)&wv[ty][kxa];
          const float* wb = (const float*)&wv[ty][kxb];
#pragma unroll
          for (int o = 0; o < 4; ++o) {
            acc[o][p] = fmaf(wa[o], sa, acc[o][p]);
            acc[o][p] = fmaf(wb[o], sb, acc[o][p]);
          }
        }
      }
    }
  }
  int opx = ox0 + px4;
  if (opx < OW) {
#pragma unroll
    for (int o = 0; o < 4; ++o) {
      int oc = oc0 + oc4 + o;
      float bv = bias[oc];
      float4 rv;
      float* rp = (float*)&rv;
#pragma unroll
      for (int p = 0; p < 4; ++p) {
        float v = (acc[o][p] + bv) * kBNF;
        rp[p] = fmaxf(v, 0.f);
      }
      *reinterpret_cast<float4*>(&out[((size_t)oc * OH + oy) * OW + opx]) = rv;
    }
  }
}

// ---------------------------------------------------------------- final 3x3 conv 128->1 + sigmoid (B=1)
__global__ __launch_bounds__(320) void dow_k(const float* __restrict__ in,
                                             const float* __restrict__ w,
                                             const float* __restrict__ bias,
                                             float* __restrict__ out) {
  const int H = 320, W = 320, IC = 128;
  int oy = blockIdx.x;
  int tx = threadIdx.x;
  __shared__ float in_s[4][3][W + 2];
  __shared__ float w_s[IC * 9];
  for (int e = tx; e < IC * 9; e += 320) w_s[e] = w[e];
  float acc = 0.f;
  for (int ic0 = 0; ic0 < IC; ic0 += 4) {
    __syncthreads();
    for (int e = tx; e < 4 * 3 * (W + 2); e += 320) {
      int icr = e / (3 * (W + 2));
      int rem = e - icr * (3 * (W + 2));
      int r = rem / (W + 2), c = rem - r * (W + 2);
      int iy = oy + r - 1, ix = c - 1;
      float v = 0.f;
      if (iy >= 0 && iy < H && ix >= 0 && ix < W)
        v = in[((ic0 + icr) * H + iy) * W + ix];
      in_s[icr][r][c] = v;
    }
    __syncthreads();
#pragma unroll
    for (int icr = 0; icr < 4; ++icr)
#pragma unroll
      for (int r = 0; r < 3; ++r)
#pragma unroll
        for (int c = 0; c < 3; ++c)
          acc = fmaf(w_s[(ic0 + icr) * 9 + r * 3 + c], in_s[icr][r][tx + c], acc);
  }
  acc += bias[0];
  out[oy * W + tx] = 1.f / (1.f + expf(-acc));
}

// ---------------------------------------------------------------- codebook sq-norms: numpy-pairwise fp32
__global__ __launch_bounds__(256) void cbprep_np(const float* __restrict__ cb,
                                                 float* __restrict__ c2f) {
  int e = blockIdx.x, t = threadIdx.x;
  __shared__ float a[256];
  a[t] = cb[e * 256 + t];
  __syncthreads();
  if (t == 0) {
    float tot = 0.f;
    for (int h = 0; h < 2; ++h) {
      const float* p = a + h * 128;
      float r[8];
#pragma unroll
      for (int j = 0; j < 8; ++j) r[j] = __fmul_rn(p[j], p[j]);
      for (int i = 8; i < 128; i += 8)
#pragma unroll
        for (int j = 0; j < 8; ++j) r[j] = __fadd_rn(r[j], __fmul_rn(p[i + j], p[i + j]));
      float s = __fadd_rn(__fadd_rn(__fadd_rn(r[0], r[1]), __fadd_rn(r[2], r[3])),
                          __fadd_rn(__fadd_rn(r[4], r[5]), __fadd_rn(r[6], r[7])));
      tot = (h == 0) ? s : __fadd_rn(tot, s);
    }
    c2f[e] = tot;
  }
}

// ---------------------------------------------------------------- VQ: block-per-row, emulated fp32 ref dist
__global__ __launch_bounds__(256) void vq_ref_k(const float* __restrict__ z,
                                                const float* __restrict__ cb,
                                                const float* __restrict__ c2f,
                                                float* __restrict__ zq_out,
                                                float* __restrict__ idx_out) {
  int row = blockIdx.x;
  int t = threadIdx.x;
  __shared__ float f[256];
  __shared__ float dist[1024];
  __shared__ float f2s;
  __shared__ int bestIdx;
  f[t] = z[(size_t)row * 256 + t];
  __syncthreads();
  if (t == 0) {
    float tot = 0.f;
    for (int h = 0; h < 2; ++h) {
      const float* p = f + h * 128;
      float r[8];
#pragma unroll
      for (int j = 0; j < 8; ++j) r[j] = __fmul_rn(p[j], p[j]);
      for (int i = 8; i < 128; i += 8)
#pragma unroll
        for (int j = 0; j < 8; ++j) r[j] = __fadd_rn(r[j], __fmul_rn(p[i + j], p[i + j]));
      float s = __fadd_rn(__fadd_rn(__fadd_rn(r[0], r[1]), __fadd_rn(r[2], r[3])),
                          __fadd_rn(__fadd_rn(r[4], r[5]), __fadd_rn(r[6], r[7])));
      tot = (h == 0) ? s : __fadd_rn(tot, s);
    }
    f2s = tot;
  }
  __syncthreads();
  float f2 = f2s;
  for (int e = t; e < 1024; e += 256) {
    const float* cbe = cb + (size_t)e * 256;
    double dot = 0.0;
    for (int d = 0; d < 256; ++d)
      dot = fma((double)f[d], (double)cbe[d], dot);
    float C = __fmul_rn(2.f, (float)dot);
    dist[e] = __fsub_rn(__fadd_rn(f2, c2f[e]), C);
  }
  __syncthreads();
  if (t == 0) {
    float bv = dist[0];
    int bi = 0;
    for (int e = 1; e < 1024; ++e)
      if (dist[e] < bv) { bv = dist[e]; bi = e; }
    bestIdx = bi;
    idx_out[row] = (float)bi;
  }
  __syncthreads();
  zq_out[(size_t)row * 256 + t] = cb[(size_t)bestIdx * 256 + t];
}

// ================================================================ host
extern "C" void kernel_launch(void* const* d_in, const int* in_sizes, int n_in,
                              void* d_out, int out_size, void* d_ws, size_t ws_size,
                              hipStream_t stream) {
  const float* x = (const float*)d_in[0];
  const float* w0 = (const float*)d_in[1];
  const float* b0 = (const float*)d_in[2];
  const float* a_c1w = (const float*)d_in[3];
  const float* a_c1b = (const float*)d_in[4];
  const float* a_c2w = (const float*)d_in[5];
  const float* a_c2b = (const float*)d_in[6];
  const float* a_scw = (const float*)d_in[7];
  const float* a_scb = (const float*)d_in[8];
  const float* b_c1w = (const float*)d_in[9];
  const float* b_c1b = (const float*)d_in[10];
  const float* b_c2w = (const float*)d_in[11];
  const float* b_c2b = (const float*)d_in[12];
  const float* b_scw = (const float*)d_in[13];
  const float* b_scb = (const float*)d_in[14];
  const float* ew = (const float*)d_in[15];
  const float* eb = (const float*)d_in[16];
  const float* cb = (const float*)d_in[17];
  const float* d0w = (const float*)d_in[18];
  const float* d0b = (const float*)d_in[19];
  const float* dt1w = (const float*)d_in[20];
  const float* dt1b = (const float*)d_in[21];
  const float* dt2w = (const float*)d_in[22];
  const float* dt2b = (const float*)d_in[23];
  const float* doww = (const float*)d_in[24];
  const float* dob = (const float*)d_in[25];

  // ws (floats): A 13.1M | B 6.55M | C 6.55M | c2f 1024  ~= 105 MB (unchanged)
  float* ws = (float*)d_ws;
  float* A = ws;
  float* Bf = ws + 13107200;
  float* Cf = ws + 19660800;
  float* c2f = ws + 26214400;
  float* w2dt1 = A;              // dead region during decoder
  float* w2dt2 = Bf + 3400000;   // past g0's 3.28M floats

  float* outf = (float*)d_out;
  float* recon = outf;
  float* zq = outf + 409600;
  float* idxo = zq + 6553600;

  cbprep_np<<<1024, 256, 0, stream>>>(cb, c2f);

  for (int b = 0; b < 4; ++b) {
    const float* xb = x + (size_t)b * 102400;
    float* zqb = zq + (size_t)b * 1638400;
    float* idxb = idxo + (size_t)b * 6400;
    float* reconb = recon + (size_t)b * 102400;

    // encoder (fp64 acc; FMA order per output unchanged -> bit-exact z)
    conv0_k<<<320, 320, 0, stream>>>(xb, w0, b0, A);
    conv3x3_k<2, true, false><<<dim3(3, 160, 4), 128, 0, stream>>>(
        A, a_c1w, a_c1b, nullptr, Bf, 128, 320, 320, 256, 160, 160);
    conv1x1_k<2, false><<<dim3(400, 4), 256, 0, stream>>>(
        A, a_scw, a_scb, Cf, 128, 320, 320, 256, 160, 160);
    conv3x3_k<1, true, true><<<dim3(3, 160, 4), 128, 0, stream>>>(
        Bf, a_c2w, a_c2b, Cf, A, 256, 160, 160, 256, 160, 160);
    conv3x3_k<2, true, false><<<dim3(2, 80, 8), 128, 0, stream>>>(
        A, b_c1w, b_c1b, nullptr, Bf, 256, 160, 160, 512, 80, 80);
    conv1x1_k<2, false><<<dim3(100, 8), 256, 0, stream>>>(
        A, b_scw, b_scb, Cf, 256, 160, 160, 512, 80, 80);
    conv3x3_k<1, true, true><<<dim3(2, 80, 8), 128, 0, stream>>>(
        Bf, b_c2w, b_c2b, Cf, A, 512, 80, 80, 512, 80, 80);
    conv1x1_k<1, false><<<dim3(100, 4), 256, 0, stream>>>(
        A, ew, eb, Cf, 512, 80, 80, 256, 80, 80);
    // VQ (unchanged)
    vq_ref_k<<<6400, 256, 0, stream>>>(Cf, cb, c2f, zqb, idxb);
    // decoder
    prep_w2_k<<<8192, 256, 0, stream>>>(dt1w, w2dt1, 512, 256);
    prep_w2_k<<<2048, 256, 0, stream>>>(dt2w, w2dt2, 256, 128);
    conv1x1_k<1, true><<<dim3(100, 8), 256, 0, stream>>>(
        zqb, d0w, d0b, Bf, 256, 80, 80, 512, 80, 80);
    convt_k<<<dim3(3, 160, 4), 256, 0, stream>>>(
        Bf, w2dt1, dt1b, Cf, 512, 80, 80, 256, 160, 160);
    convt_k<<<dim3(5, 320, 2), 256, 0, stream>>>(
        Cf, w2dt2, dt2b, A, 256, 160, 160, 128, 320, 320);
    dow_k<<<320, 320, 0, stream>>>(A, doww, dob, reconb);
  }
}

// Round 9
// 20456.583 us; speedup vs baseline: 1.3960x; 1.3960x over previous
//
#include <hip/hip_runtime.h>
#include <math.h>

// Round 9: PRECISION PROBE — encoder convs in fp32 (was fp64-acc).
// Evidence: R5/R7 matched numpy argmin bit-for-bit although my z differs from
// numpy's z at few-ulp level -> fp32-grid argmin is robust to small z noise.
// H3: fp32-accumulated z (~1e-5 rel noise) keeps all 25600 argmins identical.
// VQ emulation (numpy-pairwise f2/c2, fp64-rounded dot, fp32 dist grid,
// first-index argmin), convt/dow/decoder, ws layout: IDENTICAL to passing R7.
// Fallback if this fails: R7 (25.2 ms, fp64 encoder).

static constexpr float kBNF = 0.9999950000374997f;

// ---------------------------------------------------------------- conv0: 1->128, 3x3, s1, relu (B=1), fp32
__global__ __launch_bounds__(320) void conv0_k(const float* __restrict__ x,
                                               const float* __restrict__ w,
                                               const float* __restrict__ b,
                                               float* __restrict__ out) {
  const int H = 320, W = 320, OC = 128;
  int oy = blockIdx.x;
  int tx = threadIdx.x;
  __shared__ float in_s[3][W + 2];
  __shared__ float w_s[128 * 9];
  __shared__ float b_s[128];
  for (int e = tx; e < 3 * (W + 2); e += 320) {
    int r = e / (W + 2), c = e % (W + 2);
    int iy = oy + r - 1, ix = c - 1;
    float v = 0.f;
    if (iy >= 0 && iy < H && ix >= 0 && ix < W) v = x[iy * W + ix];
    in_s[r][c] = v;
  }
  for (int e = tx; e < 128 * 9; e += 320) w_s[e] = w[e];
  for (int e = tx; e < 128; e += 320) b_s[e] = b[e];
  __syncthreads();
  float iv[9];
#pragma unroll
  for (int r = 0; r < 3; ++r)
#pragma unroll
    for (int c = 0; c < 3; ++c) iv[r * 3 + c] = in_s[r][tx + c];
  for (int oc = 0; oc < OC; ++oc) {
    float acc = 0.f;
#pragma unroll
    for (int t = 0; t < 9; ++t) acc = fmaf(w_s[oc * 9 + t], iv[t], acc);
    float v32 = __fadd_rn(acc, b_s[oc]);
    v32 = __fmul_rn(v32, kBNF);
    out[(oc * H + oy) * W + tx] = fmaxf(v32, 0.f);
  }
}

// ---------------------------------------------------------------- 3x3 conv fp32: 64px x 64oc, 4px x 4oc/thread
template <int S, bool RELU, bool HAS_SKIP>
__global__ __launch_bounds__(256) void conv3x3_k(
    const float* __restrict__ in, const float* __restrict__ w,
    const float* __restrict__ bias, const float* __restrict__ skip,
    float* __restrict__ out, int IC, int IH, int IW, int OC, int OH, int OW) {
  // S=1: in_f[icr][ky][68] plain cols (66 used)
  // S=2: in_f[icr][ky][136]: [0..67]=even cols, [68..135]=odd cols
  __shared__ float in_f[4][3][(S == 1) ? 68 : 136];
  __shared__ float w_f[4][9][64];
  int t = threadIdx.x;
  int ox0 = blockIdx.x * 64;
  int oy = blockIdx.y;
  int oc0 = blockIdx.z * 64;
  int oc4 = (t >> 4) * 4, px4 = (t & 15) * 4;
  float acc[4][4] = {};
  const int NCOL = 64 * S + 2;  // 66 or 130
  const int NIN = 4 * 3 * NCOL;
  for (int ic0 = 0; ic0 < IC; ic0 += 4) {
    __syncthreads();
    for (int e = t; e < NIN; e += 256) {
      int icr = e / (3 * NCOL);
      int rem = e - icr * (3 * NCOL);
      int r = rem / NCOL, c = rem - r * NCOL;
      int iy = oy * S - 1 + r;
      int ix = ox0 * S - 1 + c;
      float v = 0.f;
      if (iy >= 0 && iy < IH && ix >= 0 && ix < IW)
        v = in[((ic0 + icr) * IH + iy) * IW + ix];
      if (S == 1)
        in_f[icr][r][c] = v;
      else
        in_f[icr][r][(c & 1) * 68 + (c >> 1)] = v;
    }
    for (int e = t; e < 4 * 9 * 64; e += 256) {
      int ocr = e & 63;
      int rem = e >> 6;
      int tap = rem % 9, icr = rem / 9;
      w_f[icr][tap][ocr] = w[((oc0 + ocr) * IC + ic0 + icr) * 9 + tap];
    }
    __syncthreads();
#pragma unroll
    for (int icr = 0; icr < 4; ++icr) {
#pragma unroll
      for (int ky = 0; ky < 3; ++ky) {
        float iv[9];
        if (S == 1) {
          float4 va = *reinterpret_cast<const float4*>(&in_f[icr][ky][px4]);
          float2 vb = *reinterpret_cast<const float2*>(&in_f[icr][ky][px4 + 4]);
          iv[0] = va.x; iv[1] = va.y; iv[2] = va.z;
          iv[3] = va.w; iv[4] = vb.x; iv[5] = vb.y;
        } else {
          float4 ve = *reinterpret_cast<const float4*>(&in_f[icr][ky][px4]);
          float se = in_f[icr][ky][px4 + 4];
          float4 vo = *reinterpret_cast<const float4*>(&in_f[icr][ky][68 + px4]);
          iv[0] = ve.x; iv[1] = ve.y; iv[2] = ve.z;
          iv[3] = ve.w; iv[4] = se;
          iv[5] = vo.x; iv[6] = vo.y; iv[7] = vo.z; iv[8] = vo.w;
        }
#pragma unroll
        for (int kx = 0; kx < 3; ++kx) {
          float4 wv = *reinterpret_cast<const float4*>(&w_f[icr][ky * 3 + kx][oc4]);
          const float* wp = (const float*)&wv;
#pragma unroll
          for (int p = 0; p < 4; ++p) {
            float ivv;
            if (S == 1) {
              ivv = iv[p + kx];
            } else {
              ivv = (kx == 0) ? iv[p] : (kx == 1) ? iv[5 + p] : iv[p + 1];
            }
#pragma unroll
            for (int o = 0; o < 4; ++o)
              acc[o][p] = fmaf(wp[o], ivv, acc[o][p]);
          }
        }
      }
    }
  }
  int opx = ox0 + px4;
  if (opx < OW) {
#pragma unroll
    for (int o = 0; o < 4; ++o) {
      int oc = oc0 + oc4 + o;
      float bv = bias[oc];
      size_t base = ((size_t)oc * OH + oy) * OW + opx;
      float4 rv;
      float* rp = (float*)&rv;
#pragma unroll
      for (int p = 0; p < 4; ++p) {
        float v32 = __fadd_rn(acc[o][p], bv);
        v32 = __fmul_rn(v32, kBNF);
        if (HAS_SKIP) v32 = __fadd_rn(v32, skip[base + p]);
        if (RELU) v32 = fmaxf(v32, 0.f);
        rp[p] = v32;
      }
      *reinterpret_cast<float4*>(&out[base]) = rv;
    }
  }
}

// ---------------------------------------------------------------- 1x1 conv, fp32 acc
template <int S, bool RELU>
__global__ __launch_bounds__(256) void conv1x1_k(
    const float* __restrict__ in, const float* __restrict__ w,
    const float* __restrict__ bias, float* __restrict__ out,
    int IC, int IH, int IW, int OC, int OH, int OW) {
  __shared__ float in_s[16][64];
  __shared__ float w_s[16][64];
  const int P = OH * OW;
  int t = threadIdx.x;
  int p0 = blockIdx.x * 64;
  int oc0 = blockIdx.y * 64;
  int oc4 = (t >> 4) * 4, px4 = (t & 15) * 4;
  float acc[4][4] = {};
  for (int ic0 = 0; ic0 < IC; ic0 += 16) {
    __syncthreads();
    {
      int e = t;
#pragma unroll
      for (int k = 0; k < 4; ++k, e += 256) {
        int icr = e >> 6, pxr = e & 63;
        int p = p0 + pxr;
        float v = 0.f;
        if (p < P) {
          int oy = p / OW, ox = p % OW;
          v = in[((ic0 + icr) * IH + oy * S) * IW + ox * S];
        }
        in_s[icr][pxr] = v;
      }
      e = t;
#pragma unroll
      for (int k = 0; k < 4; ++k, e += 256) {
        int icr = e >> 6, ocr = e & 63;
        w_s[icr][ocr] = w[(oc0 + ocr) * IC + ic0 + icr];
      }
    }
    __syncthreads();
#pragma unroll
    for (int icr = 0; icr < 16; ++icr) {
      float4 iv = *reinterpret_cast<const float4*>(&in_s[icr][px4]);
      float4 wv = *reinterpret_cast<const float4*>(&w_s[icr][oc4]);
      const float* ip = (const float*)&iv;
      const float* wp = (const float*)&wv;
#pragma unroll
      for (int o = 0; o < 4; ++o)
#pragma unroll
        for (int p = 0; p < 4; ++p)
          acc[o][p] = fmaf(wp[o], ip[p], acc[o][p]);
    }
  }
  int p = p0 + px4;
  if (p < P) {
    int oy = p / OW, ox = p % OW;
#pragma unroll
    for (int o = 0; o < 4; ++o) {
      int oc = oc0 + oc4 + o;
      float bv = bias[oc];
      float4 rv;
      float* rp = (float*)&rv;
#pragma unroll
      for (int pp = 0; pp < 4; ++pp) {
        float v32 = __fadd_rn(acc[o][pp], bv);
        v32 = __fmul_rn(v32, kBNF);
        if (RELU) v32 = fmaxf(v32, 0.f);
        rp[pp] = v32;
      }
      *reinterpret_cast<float4*>(&out[((size_t)oc * OH + oy) * OW + ox]) = rv;
    }
  }
}

// ---------------------------------------------------------------- ConvT weight transpose: w2[kyb][ic][ty][kx][OC]
__global__ __launch_bounds__(256) void prep_w2_k(const float* __restrict__ w,
                                                 float* __restrict__ w2,
                                                 int IC, int OC) {
  int i = blockIdx.x * 256 + threadIdx.x;
  int total = IC * OC * 16;
  if (i >= total) return;
  int oc = i % OC;
  int r = i / OC;
  int kx = r & 3; r >>= 2;
  int ty = r & 1; r >>= 1;
  int ic = r % IC;
  int kyb = r / IC;
  int ky = kyb + 2 * ty;
  w2[i] = w[((size_t)ic * OC + oc) * 16 + ky * 4 + kx];
}

// ---------------------------------------------------------------- ConvTranspose2d k4 s2 p1, relu (decoder, fp32), ICS=8
__global__ __launch_bounds__(256) void convt_k(
    const float* __restrict__ in, const float* __restrict__ w2,
    const float* __restrict__ bias, float* __restrict__ out,
    int IC, int IH, int IW, int OC, int OH, int OW) {
  __shared__ float in_s[8][2][34];
  __shared__ float w_s[8][2][4][64];
  int t = threadIdx.x;
  int ox0 = blockIdx.x * 64;
  int oy = blockIdx.y;
  int oc0 = blockIdx.z * 64;
  int oc4 = (t >> 4) * 4, px4 = (t & 15) * 4;
  int kyb = (oy & 1) ? 0 : 1;
  int c0 = ox0 >> 1;
  const float* w2b = w2 + (size_t)kyb * IC * 8 * OC;  // [ic][ty][kx][OC]
  float acc[4][4] = {};
  for (int ic0 = 0; ic0 < IC; ic0 += 8) {
    __syncthreads();
    for (int e = t; e < 8 * 2 * 34; e += 256) {
      int icr = e / 68;
      int rem = e - icr * 68;
      int ty = rem / 34, cc = rem - ty * 34;
      int ky = kyb + 2 * ty;
      int iy = (oy + 1 - ky) >> 1;
      int ix = c0 - 1 + cc;
      float v = 0.f;
      if (iy >= 0 && iy < IH && ix >= 0 && ix < IW)
        v = in[((ic0 + icr) * IH + iy) * IW + ix];
      in_s[icr][ty][cc] = v;
    }
    {
      int e = t;
#pragma unroll
      for (int k = 0; k < 16; ++k, e += 256) {
        int icr = e >> 9;
        int rem = e & 511;
        int ty = rem >> 8;
        int kx = (rem >> 6) & 3;
        int ocr = rem & 63;
        w_s[icr][ty][kx][ocr] =
            w2b[((((size_t)(ic0 + icr)) * 2 + ty) * 4 + kx) * OC + oc0 + ocr];
      }
    }
    __syncthreads();
#pragma unroll
    for (int icr = 0; icr < 8; ++icr) {
      float4 wv[2][4];
#pragma unroll
      for (int ty = 0; ty < 2; ++ty)
#pragma unroll
        for (int kx = 0; kx < 4; ++kx)
          wv[ty][kx] = *reinterpret_cast<const float4*>(&w_s[icr][ty][kx][oc4]);
#pragma unroll
      for (int p = 0; p < 4; ++p) {
        int hr = (px4 + p) >> 1;
        int kxa = (p & 1) ? 0 : 1;
        int kxb = (p & 1) ? 2 : 3;
        int ca = (p & 1) ? hr + 2 : hr + 1;
        int cb2 = (p & 1) ? hr + 1 : hr;
#pragma unroll
        for (int ty = 0; ty < 2; ++ty) {
          float sa = in_s[icr][ty][ca];
          float sb = in_s[icr][ty][cb2];
          const float* wa = (const float*)&wv[ty][kxa];
          const float* wb = (const float*)&wv[ty][kxb];
#pragma unroll
          for (int o = 0; o < 4; ++o) {
            acc[o][p] = fmaf(wa[o], sa, acc[o][p]);
            acc[o][p] = fmaf(wb[o], sb, acc[o][p]);
          }
        }
      }
    }
  }
  int opx = ox0 + px4;
  if (opx < OW) {
#pragma unroll
    for (int o = 0; o < 4; ++o) {
      int oc = oc0 + oc4 + o;
      float bv = bias[oc];
      float4 rv;
      float* rp = (float*)&rv;
#pragma unroll
      for (int p = 0; p < 4; ++p) {
        float v = (acc[o][p] + bv) * kBNF;
        rp[p] = fmaxf(v, 0.f);
      }
      *reinterpret_cast<float4*>(&out[((size_t)oc * OH + oy) * OW + opx]) = rv;
    }
  }
}

// ---------------------------------------------------------------- final 3x3 conv 128->1 + sigmoid (B=1)
__global__ __launch_bounds__(320) void dow_k(const float* __restrict__ in,
                                             const float* __restrict__ w,
                                             const float* __restrict__ bias,
                                             float* __restrict__ out) {
  const int H = 320, W = 320, IC = 128;
  int oy = blockIdx.x;
  int tx = threadIdx.x;
  __shared__ float in_s[4][3][W + 2];
  __shared__ float w_s[IC * 9];
  for (int e = tx; e < IC * 9; e += 320) w_s[e] = w[e];
  float acc = 0.f;
  for (int ic0 = 0; ic0 < IC; ic0 += 4) {
    __syncthreads();
    for (int e = tx; e < 4 * 3 * (W + 2); e += 320) {
      int icr = e / (3 * (W + 2));
      int rem = e - icr * (3 * (W + 2));
      int r = rem / (W + 2), c = rem - r * (W + 2);
      int iy = oy + r - 1, ix = c - 1;
      float v = 0.f;
      if (iy >= 0 && iy < H && ix >= 0 && ix < W)
        v = in[((ic0 + icr) * H + iy) * W + ix];
      in_s[icr][r][c] = v;
    }
    __syncthreads();
#pragma unroll
    for (int icr = 0; icr < 4; ++icr)
#pragma unroll
      for (int r = 0; r < 3; ++r)
#pragma unroll
        for (int c = 0; c < 3; ++c)
          acc = fmaf(w_s[(ic0 + icr) * 9 + r * 3 + c], in_s[icr][r][tx + c], acc);
  }
  acc += bias[0];
  out[oy * W + tx] = 1.f / (1.f + expf(-acc));
}

// ---------------------------------------------------------------- codebook sq-norms: numpy-pairwise fp32
__global__ __launch_bounds__(256) void cbprep_np(const float* __restrict__ cb,
                                                 float* __restrict__ c2f) {
  int e = blockIdx.x, t = threadIdx.x;
  __shared__ float a[256];
  a[t] = cb[e * 256 + t];
  __syncthreads();
  if (t == 0) {
    float tot = 0.f;
    for (int h = 0; h < 2; ++h) {
      const float* p = a + h * 128;
      float r[8];
#pragma unroll
      for (int j = 0; j < 8; ++j) r[j] = __fmul_rn(p[j], p[j]);
      for (int i = 8; i < 128; i += 8)
#pragma unroll
        for (int j = 0; j < 8; ++j) r[j] = __fadd_rn(r[j], __fmul_rn(p[i + j], p[i + j]));
      float s = __fadd_rn(__fadd_rn(__fadd_rn(r[0], r[1]), __fadd_rn(r[2], r[3])),
                          __fadd_rn(__fadd_rn(r[4], r[5]), __fadd_rn(r[6], r[7])));
      tot = (h == 0) ? s : __fadd_rn(tot, s);
    }
    c2f[e] = tot;
  }
}

// ---------------------------------------------------------------- VQ: block-per-row, emulated fp32 ref dist (UNCHANGED)
__global__ __launch_bounds__(256) void vq_ref_k(const float* __restrict__ z,
                                                const float* __restrict__ cb,
                                                const float* __restrict__ c2f,
                                                float* __restrict__ zq_out,
                                                float* __restrict__ idx_out) {
  int row = blockIdx.x;
  int t = threadIdx.x;
  __shared__ float f[256];
  __shared__ float dist[1024];
  __shared__ float f2s;
  __shared__ int bestIdx;
  f[t] = z[(size_t)row * 256 + t];
  __syncthreads();
  if (t == 0) {
    float tot = 0.f;
    for (int h = 0; h < 2; ++h) {
      const float* p = f + h * 128;
      float r[8];
#pragma unroll
      for (int j = 0; j < 8; ++j) r[j] = __fmul_rn(p[j], p[j]);
      for (int i = 8; i < 128; i += 8)
#pragma unroll
        for (int j = 0; j < 8; ++j) r[j] = __fadd_rn(r[j], __fmul_rn(p[i + j], p[i + j]));
      float s = __fadd_rn(__fadd_rn(__fadd_rn(r[0], r[1]), __fadd_rn(r[2], r[3])),
                          __fadd_rn(__fadd_rn(r[4], r[5]), __fadd_rn(r[6], r[7])));
      tot = (h == 0) ? s : __fadd_rn(tot, s);
    }
    f2s = tot;
  }
  __syncthreads();
  float f2 = f2s;
  for (int e = t; e < 1024; e += 256) {
    const float* cbe = cb + (size_t)e * 256;
    double dot = 0.0;
    for (int d = 0; d < 256; ++d)
      dot = fma((double)f[d], (double)cbe[d], dot);
    float C = __fmul_rn(2.f, (float)dot);
    dist[e] = __fsub_rn(__fadd_rn(f2, c2f[e]), C);
  }
  __syncthreads();
  if (t == 0) {
    float bv = dist[0];
    int bi = 0;
    for (int e = 1; e < 1024; ++e)
      if (dist[e] < bv) { bv = dist[e]; bi = e; }
    bestIdx = bi;
    idx_out[row] = (float)bi;
  }
  __syncthreads();
  zq_out[(size_t)row * 256 + t] = cb[(size_t)bestIdx * 256 + t];
}

// ================================================================ host
extern "C" void kernel_launch(void* const* d_in, const int* in_sizes, int n_in,
                              void* d_out, int out_size, void* d_ws, size_t ws_size,
                              hipStream_t stream) {
  const float* x = (const float*)d_in[0];
  const float* w0 = (const float*)d_in[1];
  const float* b0 = (const float*)d_in[2];
  const float* a_c1w = (const float*)d_in[3];
  const float* a_c1b = (const float*)d_in[4];
  const float* a_c2w = (const float*)d_in[5];
  const float* a_c2b = (const float*)d_in[6];
  const float* a_scw = (const float*)d_in[7];
  const float* a_scb = (const float*)d_in[8];
  const float* b_c1w = (const float*)d_in[9];
  const float* b_c1b = (const float*)d_in[10];
  const float* b_c2w = (const float*)d_in[11];
  const float* b_c2b = (const float*)d_in[12];
  const float* b_scw = (const float*)d_in[13];
  const float* b_scb = (const float*)d_in[14];
  const float* ew = (const float*)d_in[15];
  const float* eb = (const float*)d_in[16];
  const float* cb = (const float*)d_in[17];
  const float* d0w = (const float*)d_in[18];
  const float* d0b = (const float*)d_in[19];
  const float* dt1w = (const float*)d_in[20];
  const float* dt1b = (const float*)d_in[21];
  const float* dt2w = (const float*)d_in[22];
  const float* dt2b = (const float*)d_in[23];
  const float* doww = (const float*)d_in[24];
  const float* dob = (const float*)d_in[25];

  // ws (floats): A 13.1M | B 6.55M | C 6.55M | c2f 1024  ~= 105 MB (unchanged)
  float* ws = (float*)d_ws;
  float* A = ws;
  float* Bf = ws + 13107200;
  float* Cf = ws + 19660800;
  float* c2f = ws + 26214400;
  float* w2dt1 = A;              // dead region during decoder
  float* w2dt2 = Bf + 3400000;   // past g0's 3.28M floats

  float* outf = (float*)d_out;
  float* recon = outf;
  float* zq = outf + 409600;
  float* idxo = zq + 6553600;

  cbprep_np<<<1024, 256, 0, stream>>>(cb, c2f);

  for (int b = 0; b < 4; ++b) {
    const float* xb = x + (size_t)b * 102400;
    float* zqb = zq + (size_t)b * 1638400;
    float* idxb = idxo + (size_t)b * 6400;
    float* reconb = recon + (size_t)b * 102400;

    // encoder (fp32 acc — the probe)
    conv0_k<<<320, 320, 0, stream>>>(xb, w0, b0, A);
    conv3x3_k<2, true, false><<<dim3(3, 160, 4), 256, 0, stream>>>(
        A, a_c1w, a_c1b, nullptr, Bf, 128, 320, 320, 256, 160, 160);
    conv1x1_k<2, false><<<dim3(400, 4), 256, 0, stream>>>(
        A, a_scw, a_scb, Cf, 128, 320, 320, 256, 160, 160);
    conv3x3_k<1, true, true><<<dim3(3, 160, 4), 256, 0, stream>>>(
        Bf, a_c2w, a_c2b, Cf, A, 256, 160, 160, 256, 160, 160);
    conv3x3_k<2, true, false><<<dim3(2, 80, 8), 256, 0, stream>>>(
        A, b_c1w, b_c1b, nullptr, Bf, 256, 160, 160, 512, 80, 80);
    conv1x1_k<2, false><<<dim3(100, 8), 256, 0, stream>>>(
        A, b_scw, b_scb, Cf, 256, 160, 160, 512, 80, 80);
    conv3x3_k<1, true, true><<<dim3(2, 80, 8), 256, 0, stream>>>(
        Bf, b_c2w, b_c2b, Cf, A, 512, 80, 80, 512, 80, 80);
    conv1x1_k<1, false><<<dim3(100, 4), 256, 0, stream>>>(
        A, ew, eb, Cf, 512, 80, 80, 256, 80, 80);
    // VQ (unchanged emulation)
    vq_ref_k<<<6400, 256, 0, stream>>>(Cf, cb, c2f, zqb, idxb);
    // decoder (unchanged)
    prep_w2_k<<<8192, 256, 0, stream>>>(dt1w, w2dt1, 512, 256);
    prep_w2_k<<<2048, 256, 0, stream>>>(dt2w, w2dt2, 256, 128);
    conv1x1_k<1, true><<<dim3(100, 8), 256, 0, stream>>>(
        zqb, d0w, d0b, Bf, 256, 80, 80, 512, 80, 80);
    convt_k<<<dim3(3, 160, 4), 256, 0, stream>>>(
        Bf, w2dt1, dt1b, Cf, 512, 80, 80, 256, 160, 160);
    convt_k<<<dim3(5, 320, 2), 256, 0, stream>>>(
        Cf, w2dt2, dt2b, A, 256, 160, 160, 128, 320, 320);
    dow_k<<<320, 320, 0, stream>>>(A, doww, dob, reconb);
  }
}